// Round 12
// baseline (96.095 us; speedup 1.0000x reference)
//
#include <hip/hip_runtime.h>
#include <hip/hip_bf16.h>

// Problem constants: B=4, Q=256, K=256, H=512
#define B_ 4
#define Q_ 256
#define K_ 256
#define H_ 512
#define NEG (-1e9f)
// 2*log2(e): exp2(PRESCALE*x) = e^{2x}
#define PRESCALE 2.885390081777927f

typedef _Float16 half8 __attribute__((ext_vector_type(8)));
typedef float    f32x4 __attribute__((ext_vector_type(4)));

// ---------------------------------------------------------------------------
// Kernel 1: f16 MFMA projection GEMM + EXP epilogue (r10 version, reverted —
// r11's 64x32 tile doubled X re-reads and regressed).
//   z=0: Eq[b][q][h]  = exp2(PRESCALE * (query@Wq))   row-major
//   z=1: EkT[b][h][k] = exp2(PRESCALE * (key@Wk))     transposed output
// 64x64 tile, K-step 64, 512 thr, double-buffered LDS, 1 barrier/iter.
// ---------------------------------------------------------------------------
__global__ __launch_bounds__(512) void proj_kernel(
    const float* __restrict__ Xq, const float* __restrict__ Xk,
    const float* __restrict__ Wq, const float* __restrict__ Wk,
    float* __restrict__ Eq, float* __restrict__ EkT,
    const int* __restrict__ vlen)
{
    const int bx   = blockIdx.x;          // 0..31
    const int z    = bx >> 4;             // 0 = q, 1 = k
    const int row0 = (bx & 15) * 64;      // X row base (q-row or b*256+k)
    const int bb   = row0 >> 8;
    const int k0   = row0 & 255;
    if (z && k0 >= vlen[bb]) return;      // masked kp cols never read downstream

    const float* X = z ? Xk : Xq;
    const float* W = z ? Wk : Wq;

    __shared__ _Float16 Xl[2][8 * 520];
    __shared__ _Float16 Wl[2][8 * 520];

    const int col0 = blockIdx.y * 64;     // W col base (= h base)
    const int t    = threadIdx.x;
    const int lane = t & 63;
    const int wave = t >> 6;              // 0..7
    const int mw   = wave >> 1;           // 0..3 -> A-side 16-row strip
    const int nw   = wave & 1;            // 0..1 -> B-side 32-col half
    const int m    = lane & 15;
    const int kgl  = lane >> 4;           // frag k-group

    const int xr = t >> 3;                // X row 0..63
    const int xg = t & 7;                 // X k-group 0..7
    const int wc = t & 63;                // W col 0..63
    const int wg = t >> 6;                // W k-group 0..7

    f32x4 acc[2] = {};

    float4 xv0 = *(const float4*)&X[(size_t)(row0 + xr) * H_ + xg * 8];
    float4 xv1 = *(const float4*)&X[(size_t)(row0 + xr) * H_ + xg * 8 + 4];
    float wv8[8];
    #pragma unroll
    for (int i = 0; i < 8; ++i)
        wv8[i] = W[(size_t)(wg * 8 + i) * H_ + col0 + wc];

    for (int it = 0; it < 8; ++it) {
        const int buf = it & 1;
        {
            half8 hx;
            hx[0] = (_Float16)xv0.x; hx[1] = (_Float16)xv0.y;
            hx[2] = (_Float16)xv0.z; hx[3] = (_Float16)xv0.w;
            hx[4] = (_Float16)xv1.x; hx[5] = (_Float16)xv1.y;
            hx[6] = (_Float16)xv1.z; hx[7] = (_Float16)xv1.w;
            *(half8*)&Xl[buf][xg * 520 + xr * 8] = hx;
            half8 hw;
            #pragma unroll
            for (int i = 0; i < 8; ++i) hw[i] = (_Float16)wv8[i];
            *(half8*)&Wl[buf][wg * 520 + wc * 8] = hw;
        }
        __syncthreads();
        if (it < 7) {
            const int kk = (it + 1) * 64;
            xv0 = *(const float4*)&X[(size_t)(row0 + xr) * H_ + kk + xg * 8];
            xv1 = *(const float4*)&X[(size_t)(row0 + xr) * H_ + kk + xg * 8 + 4];
            #pragma unroll
            for (int i = 0; i < 8; ++i)
                wv8[i] = W[(size_t)(kk + wg * 8 + i) * H_ + col0 + wc];
        }
        const _Float16* Asrc = z ? &Wl[buf][0] : &Xl[buf][0];
        const _Float16* Bsrc = z ? &Xl[buf][0] : &Wl[buf][0];
        #pragma unroll
        for (int ks = 0; ks < 2; ++ks) {
            const int slab = (ks * 4 + kgl) * 520;
            const half8 af = *(const half8*)&Asrc[slab + (16 * mw + m) * 8];
            #pragma unroll
            for (int nt = 0; nt < 2; ++nt) {
                const half8 bf =
                    *(const half8*)&Bsrc[slab + (nw * 32 + nt * 16 + m) * 8];
                acc[nt] = __builtin_amdgcn_mfma_f32_16x16x32_f16(af, bf, acc[nt], 0, 0, 0);
            }
        }
    }

    const int rloc = 16 * mw + kgl * 4;   // row-dim base (q-row or h)
    if (!z) {
        #pragma unroll
        for (int nt = 0; nt < 2; ++nt) {
            const int gcol = col0 + nw * 32 + nt * 16 + m;
            #pragma unroll
            for (int r = 0; r < 4; ++r)
                Eq[(size_t)(row0 + rloc + r) * H_ + gcol] =
                    __builtin_amdgcn_exp2f(acc[nt][r] * PRESCALE);
        }
    } else {
        #pragma unroll
        for (int nt = 0; nt < 2; ++nt) {
            const int gk = k0 + nw * 32 + nt * 16 + m;   // D col = k (coalesced)
            #pragma unroll
            for (int r = 0; r < 4; ++r)
                EkT[((size_t)bb * H_ + col0 + rloc + r) * K_ + gk] =
                    __builtin_amdgcn_exp2f(acc[nt][r] * PRESCALE);
        }
    }
}

// ---------------------------------------------------------------------------
// Kernel 2: fused scores -> masked softmax -> context.  TQ = 4 q-rows/block.
// grid = (Q/4, B) = (64, 4) = 256 blocks, block = 1024 (16 waves = 4/SIMD).
// Score: wave (hh = w>>3, band = 32*(w&7)) computes the PARTIAL score over
//   h in [256*hh, 256*(hh+1)) for its k-band; whole-wave skip if >= valid.
//   Partials -> sc2[hh][q][k]; softmax sums both halves. Per-wave work
//   halves, waves/SIMD doubles -> latency hiding via TLP.
//   Thread owns 4q x 4k; Ek b128 global, 2-deep group prefetch; eqh2 packed
//   [ho][s][qi]; acc = fma(wm, rcp(fma(eq,ek,1)), .); 3 shfl_xor folds.
// Softmax: waves 0..3 (row = wave), result into sc2[0][q][*].
// Context: waves 0..7 own 32-k bands (V 1-deep prefetch); waves 8..15 pass
//   barriers; 3-level LDS tree reduce.
// ---------------------------------------------------------------------------
__global__ __launch_bounds__(1024) void fused_attn(
    const float* __restrict__ Eq, const float* __restrict__ EkT,
    const float* __restrict__ value, const int* __restrict__ vlen,
    const float* __restrict__ wv, float* __restrict__ out)
{
    const int qt = blockIdx.x;        // 0..63
    const int b  = blockIdx.y;        // 0..3
    const int q0 = qt * 4;
    const int t    = threadIdx.x;
    const int wave = t >> 6;          // 0..15
    const int lane = t & 63;

    __shared__ float eqh2[8 * 260];   // [ho][s*4+qi], 8.3 KB
    __shared__ float wm2[8 * 68];     // [ho][s], 2.2 KB  (-2 * wv)
    __shared__ float sc2[2][4][K_];   // 8 KB  (partial scores, then attn in [0])
    __shared__ float ctxp[4][4][H_];  // 32 KB reduce scratch

    const int valid = vlen[b];

    // ---- one-time staging: eq (repacked, 4 q rows) + wm (repacked) ----
    if (t < 512) {
        const int qi = t >> 7, p4 = (t & 127) * 4;
        const float4 v = *(const float4*)&Eq[((size_t)b * Q_ + q0 + qi) * H_ + p4];
        const float vv[4] = {v.x, v.y, v.z, v.w};
        const int sbase = (p4 >> 3) * 4;     // p4+j stays in same 8-block
        #pragma unroll
        for (int j = 0; j < 4; ++j)
            eqh2[((p4 & 7) + j) * 260 + sbase + qi] = vv[j];
    } else if (t < 640) {
        const int i = (t - 512) * 4;
        const float4 w = *(const float4*)&wv[i];
        const float ww[4] = {w.x, w.y, w.z, w.w};
        #pragma unroll
        for (int j = 0; j < 4; ++j) {
            const int h = i + j;
            wm2[(h & 7) * 68 + (h >> 3)] = -2.f * ww[j];
        }
    }
    __syncthreads();

    // ---- score phase: 16 waves = (h-half) x (8 k-bands) ----
    const int hh   = wave >> 3;       // h-half 0/1
    const int band = (wave & 7) * 32;
    const int ho   = lane >> 3;       // h offset 0..7
    const int kg   = lane & 7;        // k group 0..7
    const int kq   = band + kg * 4;   // this thread's first k

    if (band < valid) {
        const float* ekp = EkT + ((size_t)b * H_ + hh * 256 + ho) * K_ + kq;
        const int sb = hh * 32;           // s-offset of this half
        float acc0[4] = {}, acc1[4] = {}, acc2[4] = {}, acc3[4] = {};
        float4 pe[4], n1[4], n2[4];
        #pragma unroll
        for (int p = 0; p < 4; ++p)
            pe[p] = *(const float4*)(ekp + (size_t)p * 8 * K_);
        #pragma unroll
        for (int p = 0; p < 4; ++p)
            n1[p] = *(const float4*)(ekp + (size_t)(4 + p) * 8 * K_);

        for (int g = 0; g < 8; ++g) {        // 8 groups x 4 h-steps (this half)
            if (g < 6) {
                #pragma unroll
                for (int p = 0; p < 4; ++p)
                    n2[p] = *(const float4*)(ekp + (size_t)((g + 2) * 4 + p) * 8 * K_);
            }
            const float4 wv4 = *(const float4*)&wm2[ho * 68 + sb + g * 4];
            const float wmp[4] = {wv4.x, wv4.y, wv4.z, wv4.w};
            #pragma unroll
            for (int p = 0; p < 4; ++p) {
                const float4 eq4 = *(const float4*)&eqh2[ho * 260 + (sb + g * 4 + p) * 4];
                const float ek4[4] = {pe[p].x, pe[p].y, pe[p].z, pe[p].w};
                #pragma unroll
                for (int j = 0; j < 4; ++j) {
                    const float g0 = __builtin_fmaf(eq4.x, ek4[j], 1.0f);
                    acc0[j] = __builtin_fmaf(wmp[p], __builtin_amdgcn_rcpf(g0), acc0[j]);
                    const float g1 = __builtin_fmaf(eq4.y, ek4[j], 1.0f);
                    acc1[j] = __builtin_fmaf(wmp[p], __builtin_amdgcn_rcpf(g1), acc1[j]);
                    const float g2 = __builtin_fmaf(eq4.z, ek4[j], 1.0f);
                    acc2[j] = __builtin_fmaf(wmp[p], __builtin_amdgcn_rcpf(g2), acc2[j]);
                    const float g3 = __builtin_fmaf(eq4.w, ek4[j], 1.0f);
                    acc3[j] = __builtin_fmaf(wmp[p], __builtin_amdgcn_rcpf(g3), acc3[j]);
                }
            }
            #pragma unroll
            for (int p = 0; p < 4; ++p) { pe[p] = n1[p]; n1[p] = n2[p]; }
        }
        // combine h-partials across ho groups (lane bits 3..5)
        #pragma unroll
        for (int d = 8; d < 64; d <<= 1) {
            #pragma unroll
            for (int j = 0; j < 4; ++j) {
                acc0[j] += __shfl_xor(acc0[j], d);
                acc1[j] += __shfl_xor(acc1[j], d);
                acc2[j] += __shfl_xor(acc2[j], d);
                acc3[j] += __shfl_xor(acc3[j], d);
            }
        }
        if (ho == 0) {
            *(float4*)&sc2[hh][0][kq] = make_float4(acc0[0], acc0[1], acc0[2], acc0[3]);
            *(float4*)&sc2[hh][1][kq] = make_float4(acc1[0], acc1[1], acc1[2], acc1[3]);
            *(float4*)&sc2[hh][2][kq] = make_float4(acc2[0], acc2[1], acc2[2], acc2[3]);
            *(float4*)&sc2[hh][3][kq] = make_float4(acc3[0], acc3[1], acc3[2], acc3[3]);
        }
    }
    __syncthreads();

    // ---- masked softmax (waves 0..3; row = wave); halves summed here ----
    if (wave < 4) {
        const int q = wave;
        if (valid == 0) {
            #pragma unroll
            for (int j = 0; j < 4; ++j) sc2[0][q][lane + 64 * j] = 1.0f / K_;
        } else {
            float sv[4], mx = -3e38f;
            #pragma unroll
            for (int j = 0; j < 4; ++j) {
                const int kk = lane + 64 * j;
                const float s = (kk < valid)
                    ? sc2[0][q][kk] + sc2[1][q][kk] : NEG;
                sv[j] = s;
                mx = fmaxf(mx, s);
            }
            #pragma unroll
            for (int d = 32; d; d >>= 1) mx = fmaxf(mx, __shfl_xor(mx, d));
            float ev[4], sum = 0.f;
            #pragma unroll
            for (int j = 0; j < 4; ++j) { ev[j] = __expf(sv[j] - mx); sum += ev[j]; }
            #pragma unroll
            for (int d = 32; d; d >>= 1) sum += __shfl_xor(sum, d);
            const float inv = 1.0f / sum;
            #pragma unroll
            for (int j = 0; j < 4; ++j) sc2[0][q][lane + 64 * j] = ev[j] * inv;
        }
    }
    __syncthreads();

    // ---- context: waves 0..7 own k in [32w, 32w+32), 4 q rows ----
    const int klim = (valid == 0) ? K_ : valid;
    const int h0   = lane * 8;
    float c[4][8] = {};
    if (wave < 8) {
        const int kb   = wave * 32;
        const int kend = min(32, klim - kb);
        float4 cv0, cv1;
        if (kend > 0) {
            const float4* vp = (const float4*)&value[((size_t)b * K_ + kb) * H_ + h0];
            cv0 = vp[0]; cv1 = vp[1];
        }
        for (int kc = 0; kc < kend; ++kc) {
            const int kk = kb + kc;
            float4 nv0, nv1;
            if (kc + 1 < kend) {
                const float4* vp = (const float4*)&value[((size_t)b * K_ + kk + 1) * H_ + h0];
                nv0 = vp[0]; nv1 = vp[1];
            }
            const float vr[8] = {cv0.x, cv0.y, cv0.z, cv0.w, cv1.x, cv1.y, cv1.z, cv1.w};
            const float a0 = sc2[0][0][kk], a1 = sc2[0][1][kk];
            const float a2 = sc2[0][2][kk], a3 = sc2[0][3][kk];
            #pragma unroll
            for (int j = 0; j < 8; ++j) {
                c[0][j] = __builtin_fmaf(a0, vr[j], c[0][j]);
                c[1][j] = __builtin_fmaf(a1, vr[j], c[1][j]);
                c[2][j] = __builtin_fmaf(a2, vr[j], c[2][j]);
                c[3][j] = __builtin_fmaf(a3, vr[j], c[3][j]);
            }
            cv0 = nv0; cv1 = nv1;
        }
    }

    // 3-level tree reduce over waves 0..7 (waves 8..15 pass barriers)
    #define PARK(s)                                                           \
        do {                                                                  \
            _Pragma("unroll")                                                 \
            for (int qi = 0; qi < 4; ++qi) {                                  \
                float* d = &ctxp[s][qi][h0];                                  \
                ((float4*)d)[0] = make_float4(c[qi][0], c[qi][1], c[qi][2], c[qi][3]); \
                ((float4*)d)[1] = make_float4(c[qi][4], c[qi][5], c[qi][6], c[qi][7]); \
            }                                                                 \
        } while (0)
    #define FOLD(s)                                                           \
        do {                                                                  \
            _Pragma("unroll")                                                 \
            for (int qi = 0; qi < 4; ++qi) {                                  \
                const float* d = &ctxp[s][qi][h0];                            \
                _Pragma("unroll")                                             \
                for (int j = 0; j < 8; ++j) c[qi][j] += d[j];                 \
            }                                                                 \
        } while (0)

    if (wave >= 4 && wave < 8) PARK(wave - 4);
    __syncthreads();
    if (wave < 4) FOLD(wave);
    __syncthreads();
    if (wave == 2 || wave == 3) PARK(wave - 2);
    __syncthreads();
    if (wave < 2) FOLD(wave);
    __syncthreads();
    if (wave == 1) PARK(1);
    __syncthreads();
    if (wave == 0) {
        FOLD(1);
        #pragma unroll
        for (int qi = 0; qi < 4; ++qi) {
            float* o = &out[((size_t)b * Q_ + q0 + qi) * H_ + h0];
            ((float4*)o)[0] = make_float4(c[qi][0], c[qi][1], c[qi][2], c[qi][3]);
            ((float4*)o)[1] = make_float4(c[qi][4], c[qi][5], c[qi][6], c[qi][7]);
        }
    }
    #undef PARK
    #undef FOLD
}

// ---------------------------------------------------------------------------
extern "C" void kernel_launch(void* const* d_in, const int* in_sizes, int n_in,
                              void* d_out, int out_size, void* d_ws, size_t ws_size,
                              hipStream_t stream)
{
    const float* query = (const float*)d_in[0];
    const float* key   = (const float*)d_in[1];
    const float* value = (const float*)d_in[2];
    const int*   vlen  = (const int*)  d_in[3];
    const float* Wq    = (const float*)d_in[4];
    const float* Wk    = (const float*)d_in[5];
    const float* wv    = (const float*)d_in[6];
    float*       outp  = (float*)d_out;

    float* EqBuf  = (float*)d_ws;                 // [B*Q, H] = 2 MB (e^{2q'})
    float* EkTBuf = EqBuf + (size_t)B_ * Q_ * H_; // [B, H, K] = 2 MB (e^{2k'}, transposed)

    dim3 g1(32, 8);                               // 256 blocks, 512 threads
    proj_kernel<<<g1, 512, 0, stream>>>(query, key, Wq, Wk, EqBuf, EkTBuf, vlen);

    dim3 g2(Q_ / 4, B_);                          // (64, 4), 1024 threads
    fused_attn<<<g2, 1024, 0, stream>>>(EqBuf, EkTBuf, value, vlen, wv, outp);
}

// Round 13
// 96.002 us; speedup vs baseline: 1.0010x; 1.0010x over previous
//
#include <hip/hip_runtime.h>
#include <hip/hip_bf16.h>

// Problem constants: B=4, Q=256, K=256, H=512
#define B_ 4
#define Q_ 256
#define K_ 256
#define H_ 512
#define NEG (-1e9f)
// 2*log2(e): exp2(PRESCALE*x) = e^{2x}
#define PRESCALE 2.885390081777927f

typedef _Float16 half8 __attribute__((ext_vector_type(8)));
typedef float    f32x4 __attribute__((ext_vector_type(4)));

// ---------------------------------------------------------------------------
// Kernel 1: f16 MFMA projection GEMM + EXP epilogue (r10 version, reverted —
// r11's 64x32 tile doubled X re-reads and regressed).
//   z=0: Eq[b][q][h]  = exp2(PRESCALE * (query@Wq))   row-major
//   z=1: EkT[b][h][k] = exp2(PRESCALE * (key@Wk))     transposed output
// 64x64 tile, K-step 64, 512 thr, double-buffered LDS, 1 barrier/iter.
// ---------------------------------------------------------------------------
__global__ __launch_bounds__(512) void proj_kernel(
    const float* __restrict__ Xq, const float* __restrict__ Xk,
    const float* __restrict__ Wq, const float* __restrict__ Wk,
    float* __restrict__ Eq, float* __restrict__ EkT,
    const int* __restrict__ vlen)
{
    const int bx   = blockIdx.x;          // 0..31
    const int z    = bx >> 4;             // 0 = q, 1 = k
    const int row0 = (bx & 15) * 64;      // X row base (q-row or b*256+k)
    const int bb   = row0 >> 8;
    const int k0   = row0 & 255;
    if (z && k0 >= vlen[bb]) return;      // masked kp cols never read downstream

    const float* X = z ? Xk : Xq;
    const float* W = z ? Wk : Wq;

    __shared__ _Float16 Xl[2][8 * 520];
    __shared__ _Float16 Wl[2][8 * 520];

    const int col0 = blockIdx.y * 64;     // W col base (= h base)
    const int t    = threadIdx.x;
    const int lane = t & 63;
    const int wave = t >> 6;              // 0..7
    const int mw   = wave >> 1;           // 0..3 -> A-side 16-row strip
    const int nw   = wave & 1;            // 0..1 -> B-side 32-col half
    const int m    = lane & 15;
    const int kgl  = lane >> 4;           // frag k-group

    const int xr = t >> 3;                // X row 0..63
    const int xg = t & 7;                 // X k-group 0..7
    const int wc = t & 63;                // W col 0..63
    const int wg = t >> 6;                // W k-group 0..7

    f32x4 acc[2] = {};

    float4 xv0 = *(const float4*)&X[(size_t)(row0 + xr) * H_ + xg * 8];
    float4 xv1 = *(const float4*)&X[(size_t)(row0 + xr) * H_ + xg * 8 + 4];
    float wv8[8];
    #pragma unroll
    for (int i = 0; i < 8; ++i)
        wv8[i] = W[(size_t)(wg * 8 + i) * H_ + col0 + wc];

    for (int it = 0; it < 8; ++it) {
        const int buf = it & 1;
        {
            half8 hx;
            hx[0] = (_Float16)xv0.x; hx[1] = (_Float16)xv0.y;
            hx[2] = (_Float16)xv0.z; hx[3] = (_Float16)xv0.w;
            hx[4] = (_Float16)xv1.x; hx[5] = (_Float16)xv1.y;
            hx[6] = (_Float16)xv1.z; hx[7] = (_Float16)xv1.w;
            *(half8*)&Xl[buf][xg * 520 + xr * 8] = hx;
            half8 hw;
            #pragma unroll
            for (int i = 0; i < 8; ++i) hw[i] = (_Float16)wv8[i];
            *(half8*)&Wl[buf][wg * 520 + wc * 8] = hw;
        }
        __syncthreads();
        if (it < 7) {
            const int kk = (it + 1) * 64;
            xv0 = *(const float4*)&X[(size_t)(row0 + xr) * H_ + kk + xg * 8];
            xv1 = *(const float4*)&X[(size_t)(row0 + xr) * H_ + kk + xg * 8 + 4];
            #pragma unroll
            for (int i = 0; i < 8; ++i)
                wv8[i] = W[(size_t)(kk + wg * 8 + i) * H_ + col0 + wc];
        }
        const _Float16* Asrc = z ? &Wl[buf][0] : &Xl[buf][0];
        const _Float16* Bsrc = z ? &Xl[buf][0] : &Wl[buf][0];
        #pragma unroll
        for (int ks = 0; ks < 2; ++ks) {
            const int slab = (ks * 4 + kgl) * 520;
            const half8 af = *(const half8*)&Asrc[slab + (16 * mw + m) * 8];
            #pragma unroll
            for (int nt = 0; nt < 2; ++nt) {
                const half8 bf =
                    *(const half8*)&Bsrc[slab + (nw * 32 + nt * 16 + m) * 8];
                acc[nt] = __builtin_amdgcn_mfma_f32_16x16x32_f16(af, bf, acc[nt], 0, 0, 0);
            }
        }
    }

    const int rloc = 16 * mw + kgl * 4;   // row-dim base (q-row or h)
    if (!z) {
        #pragma unroll
        for (int nt = 0; nt < 2; ++nt) {
            const int gcol = col0 + nw * 32 + nt * 16 + m;
            #pragma unroll
            for (int r = 0; r < 4; ++r)
                Eq[(size_t)(row0 + rloc + r) * H_ + gcol] =
                    __builtin_amdgcn_exp2f(acc[nt][r] * PRESCALE);
        }
    } else {
        #pragma unroll
        for (int nt = 0; nt < 2; ++nt) {
            const int gk = k0 + nw * 32 + nt * 16 + m;   // D col = k (coalesced)
            #pragma unroll
            for (int r = 0; r < 4; ++r)
                EkT[((size_t)bb * H_ + col0 + rloc + r) * K_ + gk] =
                    __builtin_amdgcn_exp2f(acc[nt][r] * PRESCALE);
        }
    }
}

// ---------------------------------------------------------------------------
// Kernel 2: fused scores -> masked softmax -> context.  TQ = 4 q-rows/block.
// grid = (Q/4, B) = (64, 4) = 256 blocks, block = 1024 (16 waves = 4/SIMD).
// Score: wave (hh = w>>3, band = 32*(w&7)) computes the PARTIAL score over
//   h in [256*hh, 256*(hh+1)) for its k-band; whole-wave skip if >= valid.
//   Partials -> sc2[hh][q][k]; softmax sums both halves. Per-wave work
//   halves, waves/SIMD doubles -> latency hiding via TLP.
//   Thread owns 4q x 4k; Ek b128 global, 2-deep group prefetch; eqh2 packed
//   [ho][s][qi]; acc = fma(wm, rcp(fma(eq,ek,1)), .); 3 shfl_xor folds.
// Softmax: waves 0..3 (row = wave), result into sc2[0][q][*].
// Context: waves 0..7 own 32-k bands (V 1-deep prefetch); waves 8..15 pass
//   barriers; 3-level LDS tree reduce.
// ---------------------------------------------------------------------------
__global__ __launch_bounds__(1024) void fused_attn(
    const float* __restrict__ Eq, const float* __restrict__ EkT,
    const float* __restrict__ value, const int* __restrict__ vlen,
    const float* __restrict__ wv, float* __restrict__ out)
{
    const int qt = blockIdx.x;        // 0..63
    const int b  = blockIdx.y;        // 0..3
    const int q0 = qt * 4;
    const int t    = threadIdx.x;
    const int wave = t >> 6;          // 0..15
    const int lane = t & 63;

    __shared__ float eqh2[8 * 260];   // [ho][s*4+qi], 8.3 KB
    __shared__ float wm2[8 * 68];     // [ho][s], 2.2 KB  (-2 * wv)
    __shared__ float sc2[2][4][K_];   // 8 KB  (partial scores, then attn in [0])
    __shared__ float ctxp[4][4][H_];  // 32 KB reduce scratch

    const int valid = vlen[b];

    // ---- one-time staging: eq (repacked, 4 q rows) + wm (repacked) ----
    if (t < 512) {
        const int qi = t >> 7, p4 = (t & 127) * 4;
        const float4 v = *(const float4*)&Eq[((size_t)b * Q_ + q0 + qi) * H_ + p4];
        const float vv[4] = {v.x, v.y, v.z, v.w};
        const int sbase = (p4 >> 3) * 4;     // p4+j stays in same 8-block
        #pragma unroll
        for (int j = 0; j < 4; ++j)
            eqh2[((p4 & 7) + j) * 260 + sbase + qi] = vv[j];
    } else if (t < 640) {
        const int i = (t - 512) * 4;
        const float4 w = *(const float4*)&wv[i];
        const float ww[4] = {w.x, w.y, w.z, w.w};
        #pragma unroll
        for (int j = 0; j < 4; ++j) {
            const int h = i + j;
            wm2[(h & 7) * 68 + (h >> 3)] = -2.f * ww[j];
        }
    }
    __syncthreads();

    // ---- score phase: 16 waves = (h-half) x (8 k-bands) ----
    const int hh   = wave >> 3;       // h-half 0/1
    const int band = (wave & 7) * 32;
    const int ho   = lane >> 3;       // h offset 0..7
    const int kg   = lane & 7;        // k group 0..7
    const int kq   = band + kg * 4;   // this thread's first k

    if (band < valid) {
        const float* ekp = EkT + ((size_t)b * H_ + hh * 256 + ho) * K_ + kq;
        const int sb = hh * 32;           // s-offset of this half
        float acc0[4] = {}, acc1[4] = {}, acc2[4] = {}, acc3[4] = {};
        float4 pe[4], n1[4], n2[4];
        #pragma unroll
        for (int p = 0; p < 4; ++p)
            pe[p] = *(const float4*)(ekp + (size_t)p * 8 * K_);
        #pragma unroll
        for (int p = 0; p < 4; ++p)
            n1[p] = *(const float4*)(ekp + (size_t)(4 + p) * 8 * K_);

        for (int g = 0; g < 8; ++g) {        // 8 groups x 4 h-steps (this half)
            if (g < 6) {
                #pragma unroll
                for (int p = 0; p < 4; ++p)
                    n2[p] = *(const float4*)(ekp + (size_t)((g + 2) * 4 + p) * 8 * K_);
            }
            const float4 wv4 = *(const float4*)&wm2[ho * 68 + sb + g * 4];
            const float wmp[4] = {wv4.x, wv4.y, wv4.z, wv4.w};
            #pragma unroll
            for (int p = 0; p < 4; ++p) {
                const float4 eq4 = *(const float4*)&eqh2[ho * 260 + (sb + g * 4 + p) * 4];
                const float ek4[4] = {pe[p].x, pe[p].y, pe[p].z, pe[p].w};
                #pragma unroll
                for (int j = 0; j < 4; ++j) {
                    const float g0 = __builtin_fmaf(eq4.x, ek4[j], 1.0f);
                    acc0[j] = __builtin_fmaf(wmp[p], __builtin_amdgcn_rcpf(g0), acc0[j]);
                    const float g1 = __builtin_fmaf(eq4.y, ek4[j], 1.0f);
                    acc1[j] = __builtin_fmaf(wmp[p], __builtin_amdgcn_rcpf(g1), acc1[j]);
                    const float g2 = __builtin_fmaf(eq4.z, ek4[j], 1.0f);
                    acc2[j] = __builtin_fmaf(wmp[p], __builtin_amdgcn_rcpf(g2), acc2[j]);
                    const float g3 = __builtin_fmaf(eq4.w, ek4[j], 1.0f);
                    acc3[j] = __builtin_fmaf(wmp[p], __builtin_amdgcn_rcpf(g3), acc3[j]);
                }
            }
            #pragma unroll
            for (int p = 0; p < 4; ++p) { pe[p] = n1[p]; n1[p] = n2[p]; }
        }
        // combine h-partials across ho groups (lane bits 3..5)
        #pragma unroll
        for (int d = 8; d < 64; d <<= 1) {
            #pragma unroll
            for (int j = 0; j < 4; ++j) {
                acc0[j] += __shfl_xor(acc0[j], d);
                acc1[j] += __shfl_xor(acc1[j], d);
                acc2[j] += __shfl_xor(acc2[j], d);
                acc3[j] += __shfl_xor(acc3[j], d);
            }
        }
        if (ho == 0) {
            *(float4*)&sc2[hh][0][kq] = make_float4(acc0[0], acc0[1], acc0[2], acc0[3]);
            *(float4*)&sc2[hh][1][kq] = make_float4(acc1[0], acc1[1], acc1[2], acc1[3]);
            *(float4*)&sc2[hh][2][kq] = make_float4(acc2[0], acc2[1], acc2[2], acc2[3]);
            *(float4*)&sc2[hh][3][kq] = make_float4(acc3[0], acc3[1], acc3[2], acc3[3]);
        }
    }
    __syncthreads();

    // ---- masked softmax (waves 0..3; row = wave); halves summed here ----
    if (wave < 4) {
        const int q = wave;
        if (valid == 0) {
            #pragma unroll
            for (int j = 0; j < 4; ++j) sc2[0][q][lane + 64 * j] = 1.0f / K_;
        } else {
            float sv[4], mx = -3e38f;
            #pragma unroll
            for (int j = 0; j < 4; ++j) {
                const int kk = lane + 64 * j;
                const float s = (kk < valid)
                    ? sc2[0][q][kk] + sc2[1][q][kk] : NEG;
                sv[j] = s;
                mx = fmaxf(mx, s);
            }
            #pragma unroll
            for (int d = 32; d; d >>= 1) mx = fmaxf(mx, __shfl_xor(mx, d));
            float ev[4], sum = 0.f;
            #pragma unroll
            for (int j = 0; j < 4; ++j) { ev[j] = __expf(sv[j] - mx); sum += ev[j]; }
            #pragma unroll
            for (int d = 32; d; d >>= 1) sum += __shfl_xor(sum, d);
            const float inv = 1.0f / sum;
            #pragma unroll
            for (int j = 0; j < 4; ++j) sc2[0][q][lane + 64 * j] = ev[j] * inv;
        }
    }
    __syncthreads();

    // ---- context: waves 0..7 own k in [32w, 32w+32), 4 q rows ----
    const int klim = (valid == 0) ? K_ : valid;
    const int h0   = lane * 8;
    float c[4][8] = {};
    if (wave < 8) {
        const int kb   = wave * 32;
        const int kend = min(32, klim - kb);
        float4 cv0, cv1;
        if (kend > 0) {
            const float4* vp = (const float4*)&value[((size_t)b * K_ + kb) * H_ + h0];
            cv0 = vp[0]; cv1 = vp[1];
        }
        for (int kc = 0; kc < kend; ++kc) {
            const int kk = kb + kc;
            float4 nv0, nv1;
            if (kc + 1 < kend) {
                const float4* vp = (const float4*)&value[((size_t)b * K_ + kk + 1) * H_ + h0];
                nv0 = vp[0]; nv1 = vp[1];
            }
            const float vr[8] = {cv0.x, cv0.y, cv0.z, cv0.w, cv1.x, cv1.y, cv1.z, cv1.w};
            const float a0 = sc2[0][0][kk], a1 = sc2[0][1][kk];
            const float a2 = sc2[0][2][kk], a3 = sc2[0][3][kk];
            #pragma unroll
            for (int j = 0; j < 8; ++j) {
                c[0][j] = __builtin_fmaf(a0, vr[j], c[0][j]);
                c[1][j] = __builtin_fmaf(a1, vr[j], c[1][j]);
                c[2][j] = __builtin_fmaf(a2, vr[j], c[2][j]);
                c[3][j] = __builtin_fmaf(a3, vr[j], c[3][j]);
            }
            cv0 = nv0; cv1 = nv1;
        }
    }

    // 3-level tree reduce over waves 0..7 (waves 8..15 pass barriers)
    #define PARK(s)                                                           \
        do {                                                                  \
            _Pragma("unroll")                                                 \
            for (int qi = 0; qi < 4; ++qi) {                                  \
                float* d = &ctxp[s][qi][h0];                                  \
                ((float4*)d)[0] = make_float4(c[qi][0], c[qi][1], c[qi][2], c[qi][3]); \
                ((float4*)d)[1] = make_float4(c[qi][4], c[qi][5], c[qi][6], c[qi][7]); \
            }                                                                 \
        } while (0)
    #define FOLD(s)                                                           \
        do {                                                                  \
            _Pragma("unroll")                                                 \
            for (int qi = 0; qi < 4; ++qi) {                                  \
                const float* d = &ctxp[s][qi][h0];                            \
                _Pragma("unroll")                                             \
                for (int j = 0; j < 8; ++j) c[qi][j] += d[j];                 \
            }                                                                 \
        } while (0)

    if (wave >= 4 && wave < 8) PARK(wave - 4);
    __syncthreads();
    if (wave < 4) FOLD(wave);
    __syncthreads();
    if (wave == 2 || wave == 3) PARK(wave - 2);
    __syncthreads();
    if (wave < 2) FOLD(wave);
    __syncthreads();
    if (wave == 1) PARK(1);
    __syncthreads();
    if (wave == 0) {
        FOLD(1);
        #pragma unroll
        for (int qi = 0; qi < 4; ++qi) {
            float* o = &out[((size_t)b * Q_ + q0 + qi) * H_ + h0];
            ((float4*)o)[0] = make_float4(c[qi][0], c[qi][1], c[qi][2], c[qi][3]);
            ((float4*)o)[1] = make_float4(c[qi][4], c[qi][5], c[qi][6], c[qi][7]);
        }
    }
    #undef PARK
    #undef FOLD
}

// ---------------------------------------------------------------------------
extern "C" void kernel_launch(void* const* d_in, const int* in_sizes, int n_in,
                              void* d_out, int out_size, void* d_ws, size_t ws_size,
                              hipStream_t stream)
{
    const float* query = (const float*)d_in[0];
    const float* key   = (const float*)d_in[1];
    const float* value = (const float*)d_in[2];
    const int*   vlen  = (const int*)  d_in[3];
    const float* Wq    = (const float*)d_in[4];
    const float* Wk    = (const float*)d_in[5];
    const float* wv    = (const float*)d_in[6];
    float*       outp  = (float*)d_out;

    float* EqBuf  = (float*)d_ws;                 // [B*Q, H] = 2 MB (e^{2q'})
    float* EkTBuf = EqBuf + (size_t)B_ * Q_ * H_; // [B, H, K] = 2 MB (e^{2k'}, transposed)

    dim3 g1(32, 8);                               // 256 blocks, 512 threads
    proj_kernel<<<g1, 512, 0, stream>>>(query, key, Wq, Wk, EqBuf, EkTBuf, vlen);

    dim3 g2(Q_ / 4, B_);                          // (64, 4), 1024 threads
    fused_attn<<<g2, 1024, 0, stream>>>(EqBuf, EkTBuf, value, vlen, wv, outp);
}

// Round 14
// 46.237 us; speedup vs baseline: 2.0783x; 2.0763x over previous
//
#include <hip/hip_runtime.h>
#include <hip/hip_bf16.h>

// Problem constants: B=4, Q=256, K=256, H=512
#define B_ 4
#define Q_ 256
#define K_ 256
#define H_ 512
#define NEG (-1e9f)
// 2*log2(e): exp2(PRESCALE*x) = e^{2x}
#define PRESCALE 2.885390081777927f

typedef _Float16 half8 __attribute__((ext_vector_type(8)));
typedef float    f32x4 __attribute__((ext_vector_type(4)));

// ---------------------------------------------------------------------------
// Kernel 1: f16 MFMA projection GEMM + EXP epilogue (r10 version — measured
// ~3 us via r13's attribution; leave alone).
//   z=0: Eq[b][q][h]  = exp2(PRESCALE * (query@Wq))   row-major
//   z=1: EkT[b][h][k] = exp2(PRESCALE * (key@Wk))     transposed output
// 64x64 tile, K-step 64, 512 thr, double-buffered LDS, 1 barrier/iter.
// ---------------------------------------------------------------------------
__global__ __launch_bounds__(512) void proj_kernel(
    const float* __restrict__ Xq, const float* __restrict__ Xk,
    const float* __restrict__ Wq, const float* __restrict__ Wk,
    float* __restrict__ Eq, float* __restrict__ EkT,
    const int* __restrict__ vlen)
{
    const int bx   = blockIdx.x;          // 0..31
    const int z    = bx >> 4;             // 0 = q, 1 = k
    const int row0 = (bx & 15) * 64;      // X row base (q-row or b*256+k)
    const int bb   = row0 >> 8;
    const int k0   = row0 & 255;
    if (z && k0 >= vlen[bb]) return;      // masked kp cols never read downstream

    const float* X = z ? Xk : Xq;
    const float* W = z ? Wk : Wq;

    __shared__ _Float16 Xl[2][8 * 520];
    __shared__ _Float16 Wl[2][8 * 520];

    const int col0 = blockIdx.y * 64;     // W col base (= h base)
    const int t    = threadIdx.x;
    const int lane = t & 63;
    const int wave = t >> 6;              // 0..7
    const int mw   = wave >> 1;           // 0..3 -> A-side 16-row strip
    const int nw   = wave & 1;            // 0..1 -> B-side 32-col half
    const int m    = lane & 15;
    const int kgl  = lane >> 4;           // frag k-group

    const int xr = t >> 3;                // X row 0..63
    const int xg = t & 7;                 // X k-group 0..7
    const int wc = t & 63;                // W col 0..63
    const int wg = t >> 6;                // W k-group 0..7

    f32x4 acc[2] = {};

    float4 xv0 = *(const float4*)&X[(size_t)(row0 + xr) * H_ + xg * 8];
    float4 xv1 = *(const float4*)&X[(size_t)(row0 + xr) * H_ + xg * 8 + 4];
    float wv8[8];
    #pragma unroll
    for (int i = 0; i < 8; ++i)
        wv8[i] = W[(size_t)(wg * 8 + i) * H_ + col0 + wc];

    for (int it = 0; it < 8; ++it) {
        const int buf = it & 1;
        {
            half8 hx;
            hx[0] = (_Float16)xv0.x; hx[1] = (_Float16)xv0.y;
            hx[2] = (_Float16)xv0.z; hx[3] = (_Float16)xv0.w;
            hx[4] = (_Float16)xv1.x; hx[5] = (_Float16)xv1.y;
            hx[6] = (_Float16)xv1.z; hx[7] = (_Float16)xv1.w;
            *(half8*)&Xl[buf][xg * 520 + xr * 8] = hx;
            half8 hw;
            #pragma unroll
            for (int i = 0; i < 8; ++i) hw[i] = (_Float16)wv8[i];
            *(half8*)&Wl[buf][wg * 520 + wc * 8] = hw;
        }
        __syncthreads();
        if (it < 7) {
            const int kk = (it + 1) * 64;
            xv0 = *(const float4*)&X[(size_t)(row0 + xr) * H_ + kk + xg * 8];
            xv1 = *(const float4*)&X[(size_t)(row0 + xr) * H_ + kk + xg * 8 + 4];
            #pragma unroll
            for (int i = 0; i < 8; ++i)
                wv8[i] = W[(size_t)(kk + wg * 8 + i) * H_ + col0 + wc];
        }
        const _Float16* Asrc = z ? &Wl[buf][0] : &Xl[buf][0];
        const _Float16* Bsrc = z ? &Xl[buf][0] : &Wl[buf][0];
        #pragma unroll
        for (int ks = 0; ks < 2; ++ks) {
            const int slab = (ks * 4 + kgl) * 520;
            const half8 af = *(const half8*)&Asrc[slab + (16 * mw + m) * 8];
            #pragma unroll
            for (int nt = 0; nt < 2; ++nt) {
                const half8 bf =
                    *(const half8*)&Bsrc[slab + (nw * 32 + nt * 16 + m) * 8];
                acc[nt] = __builtin_amdgcn_mfma_f32_16x16x32_f16(af, bf, acc[nt], 0, 0, 0);
            }
        }
    }

    const int rloc = 16 * mw + kgl * 4;   // row-dim base (q-row or h)
    if (!z) {
        #pragma unroll
        for (int nt = 0; nt < 2; ++nt) {
            const int gcol = col0 + nw * 32 + nt * 16 + m;
            #pragma unroll
            for (int r = 0; r < 4; ++r)
                Eq[(size_t)(row0 + rloc + r) * H_ + gcol] =
                    __builtin_amdgcn_exp2f(acc[nt][r] * PRESCALE);
        }
    } else {
        #pragma unroll
        for (int nt = 0; nt < 2; ++nt) {
            const int gk = k0 + nw * 32 + nt * 16 + m;   // D col = k (coalesced)
            #pragma unroll
            for (int r = 0; r < 4; ++r)
                EkT[((size_t)bb * H_ + col0 + rloc + r) * K_ + gk] =
                    __builtin_amdgcn_exp2f(acc[nt][r] * PRESCALE);
        }
    }
}

// ---------------------------------------------------------------------------
// Kernel 2: fused scores -> masked softmax -> context.  TQ = 4, r10 structure.
// grid = (Q/4, B) = (64, 4) = 256 blocks, 512 thr (8 waves).
// SCORE INNER LOOP CHANGE (r13 -> r14): quad-batched reciprocal.
//   The kernel is rcp-trans-pipe-bound (VALUBusy pinned ~25% for 5 rounds;
//   TLP/traffic changes null). For each (q, 4k) quad:
//     u_j = fma(eq, ek_j, 1);  r = rcp((u0 u1)(u2 u3));
//     1/u0 = (r*p23)*u1, ... -> 17 VALU + 1 rcp per 4 elements (was 8 + 4).
//   Overflow-safe: u <= 1+1.4e8 -> product <= 4e32 < 3.4e38.
// Softmax: waves 0..3. Context: wave w owns its 32-k band, V 1-deep
//   prefetch, 3-level LDS tree reduce.
// ---------------------------------------------------------------------------
__global__ __launch_bounds__(512) void fused_attn(
    const float* __restrict__ Eq, const float* __restrict__ EkT,
    const float* __restrict__ value, const int* __restrict__ vlen,
    const float* __restrict__ wv, float* __restrict__ out)
{
    const int qt = blockIdx.x;        // 0..63
    const int b  = blockIdx.y;        // 0..3
    const int q0 = qt * 4;
    const int t    = threadIdx.x;
    const int wave = t >> 6;          // 0..7
    const int lane = t & 63;

    __shared__ float eqh2[8 * 260];   // [ho][s*4+qi], 8.3 KB
    __shared__ float wm2[8 * 68];     // [ho][s], 2.2 KB  (-2 * wv)
    __shared__ float sc[4][K_];       // 4 KB
    __shared__ float ctxp[4][4][H_];  // 32 KB reduce scratch

    const int valid = vlen[b];

    // ---- one-time staging: eq (repacked, 4 q rows) + wm (repacked) ----
    {
        const int qi = t >> 7, p4 = (t & 127) * 4;
        const float4 v = *(const float4*)&Eq[((size_t)b * Q_ + q0 + qi) * H_ + p4];
        const float vv[4] = {v.x, v.y, v.z, v.w};
        const int sbase = (p4 >> 3) * 4;
        #pragma unroll
        for (int j = 0; j < 4; ++j)
            eqh2[((p4 & 7) + j) * 260 + sbase + qi] = vv[j];
        if (t < 128) {
            const float4 w = *(const float4*)&wv[t * 4];
            const float ww[4] = {w.x, w.y, w.z, w.w};
            #pragma unroll
            for (int j = 0; j < 4; ++j) {
                const int h = t * 4 + j;
                wm2[(h & 7) * 68 + (h >> 3)] = -2.f * ww[j];
            }
        }
    }
    __syncthreads();

    // ---- score phase ----
    const int band = wave * 32;
    const int ho   = lane >> 3;       // h offset 0..7
    const int kg   = lane & 7;        // k group 0..7
    const int kq   = band + kg * 4;   // this thread's first k

    if (band < valid) {
        const float* ekp = EkT + ((size_t)b * H_ + ho) * K_ + kq;
        float acc0[4] = {}, acc1[4] = {}, acc2[4] = {}, acc3[4] = {};
        float4 pe[4], n1[4], n2[4];
        #pragma unroll
        for (int p = 0; p < 4; ++p)
            pe[p] = *(const float4*)(ekp + (size_t)p * 8 * K_);
        #pragma unroll
        for (int p = 0; p < 4; ++p)
            n1[p] = *(const float4*)(ekp + (size_t)(4 + p) * 8 * K_);

        for (int g = 0; g < 16; ++g) {        // 16 groups x 4 h-steps
            if (g < 14) {
                #pragma unroll
                for (int p = 0; p < 4; ++p)
                    n2[p] = *(const float4*)(ekp + (size_t)((g + 2) * 4 + p) * 8 * K_);
            }
            const float4 wv4 = *(const float4*)&wm2[ho * 68 + g * 4];
            const float wmp[4] = {wv4.x, wv4.y, wv4.z, wv4.w};
            #pragma unroll
            for (int p = 0; p < 4; ++p) {
                const float4 eq4 = *(const float4*)&eqh2[ho * 260 + (g * 4 + p) * 4];
                const float w = wmp[p];
                // quad-batched reciprocal: 1 rcp per 4 elements
                #define QUAD(EQ, ACC)                                           \
                    do {                                                        \
                        const float u0 = __builtin_fmaf(EQ, pe[p].x, 1.0f);     \
                        const float u1 = __builtin_fmaf(EQ, pe[p].y, 1.0f);     \
                        const float u2 = __builtin_fmaf(EQ, pe[p].z, 1.0f);     \
                        const float u3 = __builtin_fmaf(EQ, pe[p].w, 1.0f);     \
                        const float p01 = u0 * u1, p23 = u2 * u3;               \
                        const float r = __builtin_amdgcn_rcpf(p01 * p23);       \
                        const float rA = r * p23, rB = r * p01;                 \
                        ACC[0] = __builtin_fmaf(w, rA * u1, ACC[0]);            \
                        ACC[1] = __builtin_fmaf(w, rA * u0, ACC[1]);            \
                        ACC[2] = __builtin_fmaf(w, rB * u3, ACC[2]);            \
                        ACC[3] = __builtin_fmaf(w, rB * u2, ACC[3]);            \
                    } while (0)
                QUAD(eq4.x, acc0);
                QUAD(eq4.y, acc1);
                QUAD(eq4.z, acc2);
                QUAD(eq4.w, acc3);
                #undef QUAD
            }
            #pragma unroll
            for (int p = 0; p < 4; ++p) { pe[p] = n1[p]; n1[p] = n2[p]; }
        }
        // combine h-partials across ho groups (lane bits 3..5)
        #pragma unroll
        for (int d = 8; d < 64; d <<= 1) {
            #pragma unroll
            for (int j = 0; j < 4; ++j) {
                acc0[j] += __shfl_xor(acc0[j], d);
                acc1[j] += __shfl_xor(acc1[j], d);
                acc2[j] += __shfl_xor(acc2[j], d);
                acc3[j] += __shfl_xor(acc3[j], d);
            }
        }
        if (ho == 0) {
            *(float4*)&sc[0][kq] = make_float4(acc0[0], acc0[1], acc0[2], acc0[3]);
            *(float4*)&sc[1][kq] = make_float4(acc1[0], acc1[1], acc1[2], acc1[3]);
            *(float4*)&sc[2][kq] = make_float4(acc2[0], acc2[1], acc2[2], acc2[3]);
            *(float4*)&sc[3][kq] = make_float4(acc3[0], acc3[1], acc3[2], acc3[3]);
        }
    }
    __syncthreads();

    // ---- masked softmax (waves 0..3; row = wave) ----
    if (wave < 4) {
        const int q = wave;
        if (valid == 0) {
            #pragma unroll
            for (int j = 0; j < 4; ++j) sc[q][lane + 64 * j] = 1.0f / K_;
        } else {
            float sv[4], mx = -3e38f;
            #pragma unroll
            for (int j = 0; j < 4; ++j) {
                const int kk = lane + 64 * j;
                const float s = (kk < valid) ? sc[q][kk] : NEG;
                sv[j] = s;
                mx = fmaxf(mx, s);
            }
            #pragma unroll
            for (int d = 32; d; d >>= 1) mx = fmaxf(mx, __shfl_xor(mx, d));
            float ev[4], sum = 0.f;
            #pragma unroll
            for (int j = 0; j < 4; ++j) { ev[j] = __expf(sv[j] - mx); sum += ev[j]; }
            #pragma unroll
            for (int d = 32; d; d >>= 1) sum += __shfl_xor(sum, d);
            const float inv = 1.0f / sum;
            #pragma unroll
            for (int j = 0; j < 4; ++j) sc[q][lane + 64 * j] = ev[j] * inv;
        }
    }
    __syncthreads();

    // ---- context: wave w owns k in [32w, 32w+32), 4 q rows, V prefetched ----
    const int klim = (valid == 0) ? K_ : valid;
    const int kb   = wave * 32;
    const int kend = min(32, klim - kb);
    const int h0   = lane * 8;

    float c[4][8] = {};
    float4 cv0, cv1;
    if (kend > 0) {
        const float4* vp = (const float4*)&value[((size_t)b * K_ + kb) * H_ + h0];
        cv0 = vp[0]; cv1 = vp[1];
    }
    for (int kc = 0; kc < kend; ++kc) {
        const int kk = kb + kc;
        float4 nv0, nv1;
        if (kc + 1 < kend) {
            const float4* vp = (const float4*)&value[((size_t)b * K_ + kk + 1) * H_ + h0];
            nv0 = vp[0]; nv1 = vp[1];
        }
        const float vr[8] = {cv0.x, cv0.y, cv0.z, cv0.w, cv1.x, cv1.y, cv1.z, cv1.w};
        const float a0 = sc[0][kk], a1 = sc[1][kk], a2 = sc[2][kk], a3 = sc[3][kk];
        #pragma unroll
        for (int j = 0; j < 8; ++j) {
            c[0][j] = __builtin_fmaf(a0, vr[j], c[0][j]);
            c[1][j] = __builtin_fmaf(a1, vr[j], c[1][j]);
            c[2][j] = __builtin_fmaf(a2, vr[j], c[2][j]);
            c[3][j] = __builtin_fmaf(a3, vr[j], c[3][j]);
        }
        cv0 = nv0; cv1 = nv1;
    }

    // 3-level tree reduce over 8 waves (4 q rows)
    #define PARK(s)                                                           \
        do {                                                                  \
            _Pragma("unroll")                                                 \
            for (int qi = 0; qi < 4; ++qi) {                                  \
                float* d = &ctxp[s][qi][h0];                                  \
                ((float4*)d)[0] = make_float4(c[qi][0], c[qi][1], c[qi][2], c[qi][3]); \
                ((float4*)d)[1] = make_float4(c[qi][4], c[qi][5], c[qi][6], c[qi][7]); \
            }                                                                 \
        } while (0)
    #define FOLD(s)                                                           \
        do {                                                                  \
            _Pragma("unroll")                                                 \
            for (int qi = 0; qi < 4; ++qi) {                                  \
                const float* d = &ctxp[s][qi][h0];                            \
                _Pragma("unroll")                                             \
                for (int j = 0; j < 8; ++j) c[qi][j] += d[j];                 \
            }                                                                 \
        } while (0)

    if (wave >= 4) PARK(wave - 4);
    __syncthreads();
    if (wave < 4) FOLD(wave);
    __syncthreads();
    if (wave == 2 || wave == 3) PARK(wave - 2);
    __syncthreads();
    if (wave < 2) FOLD(wave);
    __syncthreads();
    if (wave == 1) PARK(1);
    __syncthreads();
    if (wave == 0) {
        FOLD(1);
        #pragma unroll
        for (int qi = 0; qi < 4; ++qi) {
            float* o = &out[((size_t)b * Q_ + q0 + qi) * H_ + h0];
            ((float4*)o)[0] = make_float4(c[qi][0], c[qi][1], c[qi][2], c[qi][3]);
            ((float4*)o)[1] = make_float4(c[qi][4], c[qi][5], c[qi][6], c[qi][7]);
        }
    }
    #undef PARK
    #undef FOLD
}

// ---------------------------------------------------------------------------
extern "C" void kernel_launch(void* const* d_in, const int* in_sizes, int n_in,
                              void* d_out, int out_size, void* d_ws, size_t ws_size,
                              hipStream_t stream)
{
    const float* query = (const float*)d_in[0];
    const float* key   = (const float*)d_in[1];
    const float* value = (const float*)d_in[2];
    const int*   vlen  = (const int*)  d_in[3];
    const float* Wq    = (const float*)d_in[4];
    const float* Wk    = (const float*)d_in[5];
    const float* wv    = (const float*)d_in[6];
    float*       outp  = (float*)d_out;

    float* EqBuf  = (float*)d_ws;                 // [B*Q, H] = 2 MB (e^{2q'})
    float* EkTBuf = EqBuf + (size_t)B_ * Q_ * H_; // [B, H, K] = 2 MB (e^{2k'}, transposed)

    dim3 g1(32, 8);                               // 256 blocks, 512 threads
    proj_kernel<<<g1, 512, 0, stream>>>(query, key, Wq, Wk, EqBuf, EkTBuf, vlen);

    dim3 g2(Q_ / 4, B_);                          // (64, 4), 512 threads
    fused_attn<<<g2, 512, 0, stream>>>(EqBuf, EkTBuf, value, vlen, wv, outp);
}

// Round 15
// 45.674 us; speedup vs baseline: 2.1039x; 1.0123x over previous
//
#include <hip/hip_runtime.h>
#include <hip/hip_bf16.h>

// Problem constants: B=4, Q=256, K=256, H=512
#define B_ 4
#define Q_ 256
#define K_ 256
#define H_ 512
#define NEG (-1e9f)
// 2*log2(e): exp2(PRESCALE*x) = e^{2x}
#define PRESCALE 2.885390081777927f

typedef _Float16 half8 __attribute__((ext_vector_type(8)));
typedef float    f32x4 __attribute__((ext_vector_type(4)));

// ---------------------------------------------------------------------------
// Kernel 1: f16 MFMA projection GEMM + EXP epilogue (r10 version — measured
// ~3 us via r13's attribution; leave alone).
//   z=0: Eq[b][q][h]  = exp2(PRESCALE * (query@Wq))   row-major
//   z=1: EkT[b][h][k] = exp2(PRESCALE * (key@Wk))     transposed output
// 64x64 tile, K-step 64, 512 thr, double-buffered LDS, 1 barrier/iter.
// ---------------------------------------------------------------------------
__global__ __launch_bounds__(512) void proj_kernel(
    const float* __restrict__ Xq, const float* __restrict__ Xk,
    const float* __restrict__ Wq, const float* __restrict__ Wk,
    float* __restrict__ Eq, float* __restrict__ EkT,
    const int* __restrict__ vlen)
{
    const int bx   = blockIdx.x;          // 0..31
    const int z    = bx >> 4;             // 0 = q, 1 = k
    const int row0 = (bx & 15) * 64;      // X row base (q-row or b*256+k)
    const int bb   = row0 >> 8;
    const int k0   = row0 & 255;
    if (z && k0 >= vlen[bb]) return;      // masked kp cols never read downstream

    const float* X = z ? Xk : Xq;
    const float* W = z ? Wk : Wq;

    __shared__ _Float16 Xl[2][8 * 520];
    __shared__ _Float16 Wl[2][8 * 520];

    const int col0 = blockIdx.y * 64;     // W col base (= h base)
    const int t    = threadIdx.x;
    const int lane = t & 63;
    const int wave = t >> 6;              // 0..7
    const int mw   = wave >> 1;           // 0..3 -> A-side 16-row strip
    const int nw   = wave & 1;            // 0..1 -> B-side 32-col half
    const int m    = lane & 15;
    const int kgl  = lane >> 4;           // frag k-group

    const int xr = t >> 3;                // X row 0..63
    const int xg = t & 7;                 // X k-group 0..7
    const int wc = t & 63;                // W col 0..63
    const int wg = t >> 6;                // W k-group 0..7

    f32x4 acc[2] = {};

    float4 xv0 = *(const float4*)&X[(size_t)(row0 + xr) * H_ + xg * 8];
    float4 xv1 = *(const float4*)&X[(size_t)(row0 + xr) * H_ + xg * 8 + 4];
    float wv8[8];
    #pragma unroll
    for (int i = 0; i < 8; ++i)
        wv8[i] = W[(size_t)(wg * 8 + i) * H_ + col0 + wc];

    for (int it = 0; it < 8; ++it) {
        const int buf = it & 1;
        {
            half8 hx;
            hx[0] = (_Float16)xv0.x; hx[1] = (_Float16)xv0.y;
            hx[2] = (_Float16)xv0.z; hx[3] = (_Float16)xv0.w;
            hx[4] = (_Float16)xv1.x; hx[5] = (_Float16)xv1.y;
            hx[6] = (_Float16)xv1.z; hx[7] = (_Float16)xv1.w;
            *(half8*)&Xl[buf][xg * 520 + xr * 8] = hx;
            half8 hw;
            #pragma unroll
            for (int i = 0; i < 8; ++i) hw[i] = (_Float16)wv8[i];
            *(half8*)&Wl[buf][wg * 520 + wc * 8] = hw;
        }
        __syncthreads();
        if (it < 7) {
            const int kk = (it + 1) * 64;
            xv0 = *(const float4*)&X[(size_t)(row0 + xr) * H_ + kk + xg * 8];
            xv1 = *(const float4*)&X[(size_t)(row0 + xr) * H_ + kk + xg * 8 + 4];
            #pragma unroll
            for (int i = 0; i < 8; ++i)
                wv8[i] = W[(size_t)(kk + wg * 8 + i) * H_ + col0 + wc];
        }
        const _Float16* Asrc = z ? &Wl[buf][0] : &Xl[buf][0];
        const _Float16* Bsrc = z ? &Xl[buf][0] : &Wl[buf][0];
        #pragma unroll
        for (int ks = 0; ks < 2; ++ks) {
            const int slab = (ks * 4 + kgl) * 520;
            const half8 af = *(const half8*)&Asrc[slab + (16 * mw + m) * 8];
            #pragma unroll
            for (int nt = 0; nt < 2; ++nt) {
                const half8 bf =
                    *(const half8*)&Bsrc[slab + (nw * 32 + nt * 16 + m) * 8];
                acc[nt] = __builtin_amdgcn_mfma_f32_16x16x32_f16(af, bf, acc[nt], 0, 0, 0);
            }
        }
    }

    const int rloc = 16 * mw + kgl * 4;   // row-dim base (q-row or h)
    if (!z) {
        #pragma unroll
        for (int nt = 0; nt < 2; ++nt) {
            const int gcol = col0 + nw * 32 + nt * 16 + m;
            #pragma unroll
            for (int r = 0; r < 4; ++r)
                Eq[(size_t)(row0 + rloc + r) * H_ + gcol] =
                    __builtin_amdgcn_exp2f(acc[nt][r] * PRESCALE);
        }
    } else {
        #pragma unroll
        for (int nt = 0; nt < 2; ++nt) {
            const int gk = k0 + nw * 32 + nt * 16 + m;   // D col = k (coalesced)
            #pragma unroll
            for (int r = 0; r < 4; ++r)
                EkT[((size_t)bb * H_ + col0 + rloc + r) * K_ + gk] =
                    __builtin_amdgcn_exp2f(acc[nt][r] * PRESCALE);
        }
    }
}

// ---------------------------------------------------------------------------
// Kernel 2: fused scores -> masked softmax -> context.  TQ = 4, r10 structure.
// grid = (Q/4, B) = (64, 4) = 256 blocks, 512 thr (8 waves).
// SCORE INNER LOOP CHANGE (r13 -> r14): quad-batched reciprocal.
//   The kernel is rcp-trans-pipe-bound (VALUBusy pinned ~25% for 5 rounds;
//   TLP/traffic changes null). For each (q, 4k) quad:
//     u_j = fma(eq, ek_j, 1);  r = rcp((u0 u1)(u2 u3));
//     1/u0 = (r*p23)*u1, ... -> 17 VALU + 1 rcp per 4 elements (was 8 + 4).
//   Overflow-safe: u <= 1+1.4e8 -> product <= 4e32 < 3.4e38.
// Softmax: waves 0..3. Context: wave w owns its 32-k band, V 1-deep
//   prefetch, 3-level LDS tree reduce.
// ---------------------------------------------------------------------------
__global__ __launch_bounds__(512) void fused_attn(
    const float* __restrict__ Eq, const float* __restrict__ EkT,
    const float* __restrict__ value, const int* __restrict__ vlen,
    const float* __restrict__ wv, float* __restrict__ out)
{
    const int qt = blockIdx.x;        // 0..63
    const int b  = blockIdx.y;        // 0..3
    const int q0 = qt * 4;
    const int t    = threadIdx.x;
    const int wave = t >> 6;          // 0..7
    const int lane = t & 63;

    __shared__ float eqh2[8 * 260];   // [ho][s*4+qi], 8.3 KB
    __shared__ float wm2[8 * 68];     // [ho][s], 2.2 KB  (-2 * wv)
    __shared__ float sc[4][K_];       // 4 KB
    __shared__ float ctxp[4][4][H_];  // 32 KB reduce scratch

    const int valid = vlen[b];

    // ---- one-time staging: eq (repacked, 4 q rows) + wm (repacked) ----
    {
        const int qi = t >> 7, p4 = (t & 127) * 4;
        const float4 v = *(const float4*)&Eq[((size_t)b * Q_ + q0 + qi) * H_ + p4];
        const float vv[4] = {v.x, v.y, v.z, v.w};
        const int sbase = (p4 >> 3) * 4;
        #pragma unroll
        for (int j = 0; j < 4; ++j)
            eqh2[((p4 & 7) + j) * 260 + sbase + qi] = vv[j];
        if (t < 128) {
            const float4 w = *(const float4*)&wv[t * 4];
            const float ww[4] = {w.x, w.y, w.z, w.w};
            #pragma unroll
            for (int j = 0; j < 4; ++j) {
                const int h = t * 4 + j;
                wm2[(h & 7) * 68 + (h >> 3)] = -2.f * ww[j];
            }
        }
    }
    __syncthreads();

    // ---- score phase ----
    const int band = wave * 32;
    const int ho   = lane >> 3;       // h offset 0..7
    const int kg   = lane & 7;        // k group 0..7
    const int kq   = band + kg * 4;   // this thread's first k

    if (band < valid) {
        const float* ekp = EkT + ((size_t)b * H_ + ho) * K_ + kq;
        float acc0[4] = {}, acc1[4] = {}, acc2[4] = {}, acc3[4] = {};
        float4 pe[4], n1[4], n2[4];
        #pragma unroll
        for (int p = 0; p < 4; ++p)
            pe[p] = *(const float4*)(ekp + (size_t)p * 8 * K_);
        #pragma unroll
        for (int p = 0; p < 4; ++p)
            n1[p] = *(const float4*)(ekp + (size_t)(4 + p) * 8 * K_);

        for (int g = 0; g < 16; ++g) {        // 16 groups x 4 h-steps
            if (g < 14) {
                #pragma unroll
                for (int p = 0; p < 4; ++p)
                    n2[p] = *(const float4*)(ekp + (size_t)((g + 2) * 4 + p) * 8 * K_);
            }
            const float4 wv4 = *(const float4*)&wm2[ho * 68 + g * 4];
            const float wmp[4] = {wv4.x, wv4.y, wv4.z, wv4.w};
            #pragma unroll
            for (int p = 0; p < 4; ++p) {
                const float4 eq4 = *(const float4*)&eqh2[ho * 260 + (g * 4 + p) * 4];
                const float w = wmp[p];
                // quad-batched reciprocal: 1 rcp per 4 elements
                #define QUAD(EQ, ACC)                                           \
                    do {                                                        \
                        const float u0 = __builtin_fmaf(EQ, pe[p].x, 1.0f);     \
                        const float u1 = __builtin_fmaf(EQ, pe[p].y, 1.0f);     \
                        const float u2 = __builtin_fmaf(EQ, pe[p].z, 1.0f);     \
                        const float u3 = __builtin_fmaf(EQ, pe[p].w, 1.0f);     \
                        const float p01 = u0 * u1, p23 = u2 * u3;               \
                        const float r = __builtin_amdgcn_rcpf(p01 * p23);       \
                        const float rA = r * p23, rB = r * p01;                 \
                        ACC[0] = __builtin_fmaf(w, rA * u1, ACC[0]);            \
                        ACC[1] = __builtin_fmaf(w, rA * u0, ACC[1]);            \
                        ACC[2] = __builtin_fmaf(w, rB * u3, ACC[2]);            \
                        ACC[3] = __builtin_fmaf(w, rB * u2, ACC[3]);            \
                    } while (0)
                QUAD(eq4.x, acc0);
                QUAD(eq4.y, acc1);
                QUAD(eq4.z, acc2);
                QUAD(eq4.w, acc3);
                #undef QUAD
            }
            #pragma unroll
            for (int p = 0; p < 4; ++p) { pe[p] = n1[p]; n1[p] = n2[p]; }
        }
        // combine h-partials across ho groups (lane bits 3..5)
        #pragma unroll
        for (int d = 8; d < 64; d <<= 1) {
            #pragma unroll
            for (int j = 0; j < 4; ++j) {
                acc0[j] += __shfl_xor(acc0[j], d);
                acc1[j] += __shfl_xor(acc1[j], d);
                acc2[j] += __shfl_xor(acc2[j], d);
                acc3[j] += __shfl_xor(acc3[j], d);
            }
        }
        if (ho == 0) {
            *(float4*)&sc[0][kq] = make_float4(acc0[0], acc0[1], acc0[2], acc0[3]);
            *(float4*)&sc[1][kq] = make_float4(acc1[0], acc1[1], acc1[2], acc1[3]);
            *(float4*)&sc[2][kq] = make_float4(acc2[0], acc2[1], acc2[2], acc2[3]);
            *(float4*)&sc[3][kq] = make_float4(acc3[0], acc3[1], acc3[2], acc3[3]);
        }
    }
    __syncthreads();

    // ---- masked softmax (waves 0..3; row = wave) ----
    if (wave < 4) {
        const int q = wave;
        if (valid == 0) {
            #pragma unroll
            for (int j = 0; j < 4; ++j) sc[q][lane + 64 * j] = 1.0f / K_;
        } else {
            float sv[4], mx = -3e38f;
            #pragma unroll
            for (int j = 0; j < 4; ++j) {
                const int kk = lane + 64 * j;
                const float s = (kk < valid) ? sc[q][kk] : NEG;
                sv[j] = s;
                mx = fmaxf(mx, s);
            }
            #pragma unroll
            for (int d = 32; d; d >>= 1) mx = fmaxf(mx, __shfl_xor(mx, d));
            float ev[4], sum = 0.f;
            #pragma unroll
            for (int j = 0; j < 4; ++j) { ev[j] = __expf(sv[j] - mx); sum += ev[j]; }
            #pragma unroll
            for (int d = 32; d; d >>= 1) sum += __shfl_xor(sum, d);
            const float inv = 1.0f / sum;
            #pragma unroll
            for (int j = 0; j < 4; ++j) sc[q][lane + 64 * j] = ev[j] * inv;
        }
    }
    __syncthreads();

    // ---- context: wave w owns k in [32w, 32w+32), 4 q rows, V prefetched ----
    const int klim = (valid == 0) ? K_ : valid;
    const int kb   = wave * 32;
    const int kend = min(32, klim - kb);
    const int h0   = lane * 8;

    float c[4][8] = {};
    float4 cv0, cv1;
    if (kend > 0) {
        const float4* vp = (const float4*)&value[((size_t)b * K_ + kb) * H_ + h0];
        cv0 = vp[0]; cv1 = vp[1];
    }
    for (int kc = 0; kc < kend; ++kc) {
        const int kk = kb + kc;
        float4 nv0, nv1;
        if (kc + 1 < kend) {
            const float4* vp = (const float4*)&value[((size_t)b * K_ + kk + 1) * H_ + h0];
            nv0 = vp[0]; nv1 = vp[1];
        }
        const float vr[8] = {cv0.x, cv0.y, cv0.z, cv0.w, cv1.x, cv1.y, cv1.z, cv1.w};
        const float a0 = sc[0][kk], a1 = sc[1][kk], a2 = sc[2][kk], a3 = sc[3][kk];
        #pragma unroll
        for (int j = 0; j < 8; ++j) {
            c[0][j] = __builtin_fmaf(a0, vr[j], c[0][j]);
            c[1][j] = __builtin_fmaf(a1, vr[j], c[1][j]);
            c[2][j] = __builtin_fmaf(a2, vr[j], c[2][j]);
            c[3][j] = __builtin_fmaf(a3, vr[j], c[3][j]);
        }
        cv0 = nv0; cv1 = nv1;
    }

    // 3-level tree reduce over 8 waves (4 q rows)
    #define PARK(s)                                                           \
        do {                                                                  \
            _Pragma("unroll")                                                 \
            for (int qi = 0; qi < 4; ++qi) {                                  \
                float* d = &ctxp[s][qi][h0];                                  \
                ((float4*)d)[0] = make_float4(c[qi][0], c[qi][1], c[qi][2], c[qi][3]); \
                ((float4*)d)[1] = make_float4(c[qi][4], c[qi][5], c[qi][6], c[qi][7]); \
            }                                                                 \
        } while (0)
    #define FOLD(s)                                                           \
        do {                                                                  \
            _Pragma("unroll")                                                 \
            for (int qi = 0; qi < 4; ++qi) {                                  \
                const float* d = &ctxp[s][qi][h0];                            \
                _Pragma("unroll")                                             \
                for (int j = 0; j < 8; ++j) c[qi][j] += d[j];                 \
            }                                                                 \
        } while (0)

    if (wave >= 4) PARK(wave - 4);
    __syncthreads();
    if (wave < 4) FOLD(wave);
    __syncthreads();
    if (wave == 2 || wave == 3) PARK(wave - 2);
    __syncthreads();
    if (wave < 2) FOLD(wave);
    __syncthreads();
    if (wave == 1) PARK(1);
    __syncthreads();
    if (wave == 0) {
        FOLD(1);
        #pragma unroll
        for (int qi = 0; qi < 4; ++qi) {
            float* o = &out[((size_t)b * Q_ + q0 + qi) * H_ + h0];
            ((float4*)o)[0] = make_float4(c[qi][0], c[qi][1], c[qi][2], c[qi][3]);
            ((float4*)o)[1] = make_float4(c[qi][4], c[qi][5], c[qi][6], c[qi][7]);
        }
    }
    #undef PARK
    #undef FOLD
}

// ---------------------------------------------------------------------------
extern "C" void kernel_launch(void* const* d_in, const int* in_sizes, int n_in,
                              void* d_out, int out_size, void* d_ws, size_t ws_size,
                              hipStream_t stream)
{
    const float* query = (const float*)d_in[0];
    const float* key   = (const float*)d_in[1];
    const float* value = (const float*)d_in[2];
    const int*   vlen  = (const int*)  d_in[3];
    const float* Wq    = (const float*)d_in[4];
    const float* Wk    = (const float*)d_in[5];
    const float* wv    = (const float*)d_in[6];
    float*       outp  = (float*)d_out;

    float* EqBuf  = (float*)d_ws;                 // [B*Q, H] = 2 MB (e^{2q'})
    float* EkTBuf = EqBuf + (size_t)B_ * Q_ * H_; // [B, H, K] = 2 MB (e^{2k'}, transposed)

    dim3 g1(32, 8);                               // 256 blocks, 512 threads
    proj_kernel<<<g1, 512, 0, stream>>>(query, key, Wq, Wk, EqBuf, EkTBuf, vlen);

    dim3 g2(Q_ / 4, B_);                          // (64, 4), 512 threads
    fused_attn<<<g2, 512, 0, stream>>>(EqBuf, EkTBuf, value, vlen, wv, outp);
}